// Round 3
// baseline (4985.113 us; speedup 1.0000x reference)
//
#include <hip/hip_runtime.h>
#include <hip/hip_bf16.h>

#define T_STEPS 512
#define B_SZ    128
#define I_SZ    256
#define H_SZ    256
#define NB      16                 // batches per scan block
#define SCAN_BLOCKS (B_SZ / NB)    // 8
#define SCAN_THREADS 512

typedef __attribute__((ext_vector_type(8))) short short8;
typedef __attribute__((ext_vector_type(4))) float floatx4;
union I4S8 { uint4 u; short8 s; };

// ---- scan LDS layout ----
#define HM_G_STRIDE 8320                 // hm: g*8320 + kk*1040 + lane*16   (33280 B)
#define ST_OFF      33280
#define ST_ROW      268                  // fp32 row stride (b*4+g rows, 64 rows)
#define ULDS_OFF    (ST_OFF + 64 * ST_ROW * 4)        // 33280 + 68608 = 101888
#define ULDS_W      7168                 // 7 frags * 1024 per wave
#define SMEM_BYTES  (ULDS_OFF + 8 * ULDS_W)           // 159232  (< 160 KiB)

// ---- U-frag tiering per wave (64 frags = nt(8) x kk(8)) ----
// kk 0..3           : register-resident (32 frags)
// kk == 4, nt 0..6  : LDS (7 frags, index nt)
// rest (25 frags)   : streamed, 5-deep rotating ring that WRAPS across steps.
//   SDEPTH must divide 25 so slot = o % SDEPTH is invariant under the wrap:
//   consume ordinal o from slot o%5, refill that slot with ordinal (o+5)%25;
//   its consumer reads slot (o+5)%5 == o%5.  (SDEPTH=6 was the round-2 bug:
//   25%6=1 rotated every step's slots by one.)
// consumption order: pairs p=(nt 2p,2p+1), kk ascending, e=0,1
static constexpr int SORD[8][8] = {
    {-1,-1,-1,-1,-1, 0, 2, 4},
    {-1,-1,-1,-1,-1, 1, 3, 5},
    {-1,-1,-1,-1,-1, 6, 8,10},
    {-1,-1,-1,-1,-1, 7, 9,11},
    {-1,-1,-1,-1,-1,12,14,16},
    {-1,-1,-1,-1,-1,13,15,17},
    {-1,-1,-1,-1,-1,19,21,23},
    {-1,-1,-1,-1,18,20,22,24},
};
static constexpr int SFRG[25] = {  // ordinal -> frag linear index nt*8+kk
     5,13, 6,14, 7,15,
    21,29,22,30,23,31,
    37,45,38,46,39,47,
    60,53,61,54,62,55,63
};
#define SDEPTH 5

__device__ __forceinline__ float fast_sigmoid(float x) {
    return 1.f / (1.f + __expf(-x));
}
__device__ __forceinline__ float fast_tanh(float x) {
    float ax = fabsf(x);
    float e = __expf(-2.f * ax);
    float t = (1.f - e) / (1.f + e);
    return copysignf(t, x);
}
__device__ __forceinline__ ushort f2bf(float v) {
    __hip_bfloat16 hb = __float2bfloat16(v);
    return *(ushort*)&hb;
}
__device__ __forceinline__ float bf2f(ushort u) {
    unsigned int b = ((unsigned int)u) << 16;
    return __uint_as_float(b);
}
__device__ __forceinline__ float concrete_mask(float u) {
    const float EPS = 1e-7f;
    float logit_p = logf(0.25f + EPS) - logf(0.75f + EPS);
    float lu = logf(u + EPS) - logf(1.0f - u + EPS);
    float z = (logit_p + lu) * 10.0f;
    float sig = 1.0f / (1.0f + expf(-z));
    return (1.0f - sig) * (1.0f / 0.75f);
}

// ---------- kernel 1: masks (zx fp32, zh bf16) ----------
__global__ void mask_kernel(const float* __restrict__ ux, const float* __restrict__ uh,
                            float* __restrict__ zx, __hip_bfloat16* __restrict__ zh) {
    int idx = blockIdx.x * blockDim.x + threadIdx.x;   // 0 .. 262143
    const int n = 4 * B_SZ * I_SZ;
    if (idx < n) zx[idx] = concrete_mask(ux[idx]);
    else         zh[idx - n] = __float2bfloat16(concrete_mask(uh[idx - n]));
}

// ---------- kernel 2: swizzle a [4][256][256] fp32 matrix into MFMA B-frag bf16 ----------
// frag (g, ktile, kk): lane l holds B[k=kk*32+((l>>4)&3)*8+j][n=ktile*16+(l&15)],
// B[k][n] = M[g][n][k].  uint4 index = ((g*16+ktile)*8+kk)*64+lane.
__global__ void uswz_kernel(const float* __restrict__ M, __hip_bfloat16* __restrict__ M_sw) {
    int tId = blockIdx.x * 256 + threadIdx.x;    // 0 .. 32767
    int lane  = tId & 63;
    int kk    = (tId >> 6) & 7;
    int ktile = (tId >> 9) & 15;
    int g     = tId >> 13;
    int nCol  = ktile * 16 + (lane & 15);
    int h0    = kk * 32 + ((lane >> 4) & 3) * 8;
    const float* src = M + ((size_t)g * 256 + nCol) * 256 + h0;
    ushort o[8];
    #pragma unroll
    for (int j = 0; j < 8; ++j) o[j] = f2bf(src[j]);
    uint4 pk;
    pk.x = (uint)o[0] | ((uint)o[1] << 16);
    pk.y = (uint)o[2] | ((uint)o[3] << 16);
    pk.z = (uint)o[4] | ((uint)o[5] << 16);
    pk.w = (uint)o[6] | ((uint)o[7] << 16);
    ((uint4*)M_sw)[tId] = pk;
}

// ---------- kernel 3: x_pre via MFMA (masked input @ W^T + Wb + Ub), bf16 out ----------
// 1024 blocks x 512 thr; block: 64 M-rows x 256 N. Wave (g, khalf): 4 mtiles x 8 ntiles.
__global__ __launch_bounds__(512, 2) void xpre_mfma_kernel(
        const float* __restrict__ input, const float* __restrict__ zx,
        const __hip_bfloat16* __restrict__ W_sw,
        const float* __restrict__ Wb, const float* __restrict__ Ub,
        __hip_bfloat16* __restrict__ xpre) {
    const int tid   = threadIdx.x;
    const int w     = tid >> 6;
    const int lane  = tid & 63;
    const int g     = w >> 1;
    const int khalf = w & 1;
    const int row0  = blockIdx.x * 64;
    const int mrow  = lane & 15;
    const int kq    = lane >> 4;     // 0..3

    floatx4 acc[4][8];
    #pragma unroll
    for (int mt = 0; mt < 4; ++mt)
        #pragma unroll
        for (int nt = 0; nt < 8; ++nt)
            #pragma unroll
            for (int r = 0; r < 4; ++r) acc[mt][nt][r] = 0.f;

    const uint4* Wp = (const uint4*)W_sw + ((size_t)((g * 16 + khalf * 8) * 8)) * 64 + lane;

    for (int kc = 0; kc < 8; ++kc) {
        I4S8 af[4];
        const int i0 = kc * 32 + kq * 8;
        #pragma unroll
        for (int mt = 0; mt < 4; ++mt) {
            int row = row0 + mt * 16 + mrow;
            int b   = row & (B_SZ - 1);
            const float4* ip = (const float4*)(input + (size_t)row * I_SZ + i0);
            const float4* zp = (const float4*)(zx + ((size_t)g * B_SZ + b) * I_SZ + i0);
            float4 a0 = ip[0], a1 = ip[1];
            float4 z0 = zp[0], z1 = zp[1];
            uint4 pk;
            pk.x = (uint)f2bf(a0.x * z0.x) | ((uint)f2bf(a0.y * z0.y) << 16);
            pk.y = (uint)f2bf(a0.z * z0.z) | ((uint)f2bf(a0.w * z0.w) << 16);
            pk.z = (uint)f2bf(a1.x * z1.x) | ((uint)f2bf(a1.y * z1.y) << 16);
            pk.w = (uint)f2bf(a1.z * z1.z) | ((uint)f2bf(a1.w * z1.w) << 16);
            af[mt].u = pk;
        }
        #pragma unroll
        for (int nt = 0; nt < 8; ++nt) {
            I4S8 bb; bb.u = Wp[(nt * 8 + kc) * 64];
            #pragma unroll
            for (int mt = 0; mt < 4; ++mt)
                acc[mt][nt] = __builtin_amdgcn_mfma_f32_16x16x32_bf16(af[mt].s, bb.s, acc[mt][nt], 0, 0, 0);
        }
    }
    // epilogue: + Wb + Ub, store bf16 (C layout: row=(lane>>4)*4+r, col=lane&15)
    #pragma unroll
    for (int nt = 0; nt < 8; ++nt) {
        int col = khalf * 128 + nt * 16 + (lane & 15);
        float bias = Wb[g * H_SZ + col] + Ub[g * H_SZ + col];
        #pragma unroll
        for (int mt = 0; mt < 4; ++mt) {
            #pragma unroll
            for (int r = 0; r < 4; ++r) {
                int row = row0 + mt * 16 + (lane >> 4) * 4 + r;
                xpre[((size_t)row * 4 + g) * H_SZ + col] = __float2bfloat16(acc[mt][nt][r] + bias);
            }
        }
    }
}

// ---------- kernel 4: MFMA scan with tiered-resident U ----------
__global__ __launch_bounds__(SCAN_THREADS, 2) void scan_mfma_kernel(
        const __hip_bfloat16* __restrict__ xpre,   // [T][B][4][H], includes Wb+Ub
        const __hip_bfloat16* __restrict__ zh,     // [4][B][H] bf16
        const __hip_bfloat16* __restrict__ U_sw,   // swizzled B-frags
        float* __restrict__ out) {
    extern __shared__ __align__(16) char smem[];
    const int tid  = threadIdx.x;
    const int b0   = blockIdx.x * NB;
    const int w     = tid >> 6;
    const int lane  = tid & 63;
    const int g_w   = w >> 1;
    const int khalf = w & 1;
    // epilogue mapping
    const int be      = tid >> 5;             // 0..15 (batch)
    const int k8      = (tid & 31) * 8;       // 0..248
    const int kk_e    = k8 >> 5;
    const int lane_hm = (be & 15) | (((k8 >> 3) & 3) << 4);
    const int sw_e    = ((be >> 2) & 1) << 4; // st read un-swizzle (bit-4 XOR)

    const uint4* Uw = (const uint4*)U_sw + ((size_t)((g_w * 16 + khalf * 8) * 8)) * 64 + lane;
    float* st = (float*)(smem + ST_OFF);

    // ---- one-time fills ----
    // register-resident frags (kk 0..3)
    uint4 ures[32];
    #pragma unroll
    for (int nt = 0; nt < 8; ++nt)
        #pragma unroll
        for (int kk = 0; kk < 4; ++kk)
            ures[nt * 4 + kk] = Uw[(nt * 8 + kk) * 64];
    // LDS frags (kk==4, nt 0..6)
    #pragma unroll
    for (int f = 0; f < 7; ++f) {
        uint4 v = Uw[(f * 8 + 4) * 64];
        *(uint4*)(smem + ULDS_OFF + w * ULDS_W + f * 1024 + lane * 16) = v;
    }
    // zero hm region (h0 = 0)
    for (int i = tid; i < HM_G_STRIDE * 4 / 16; i += SCAN_THREADS)
        ((uint4*)smem)[i] = make_uint4(0u, 0u, 0u, 0u);

    // persistent epilogue registers
    uint4 zhreg[4];
    float c8[8], h8[8];
    #pragma unroll
    for (int g = 0; g < 4; ++g)
        zhreg[g] = *(const uint4*)(zh + ((size_t)g * B_SZ + (b0 + be)) * H_SZ + k8);
    #pragma unroll
    for (int j = 0; j < 8; ++j) c8[j] = 0.f;

    // software pipeline: xpre for t=0 and the first SDEPTH stream ordinals
    uint4 xpn[4];
    #pragma unroll
    for (int g = 0; g < 4; ++g)
        xpn[g] = *(const uint4*)(xpre + (((size_t)0 * B_SZ + (b0 + be)) * 4 + g) * H_SZ + k8);
    uint4 sbuf[SDEPTH];
    #pragma unroll
    for (int q = 0; q < SDEPTH; ++q) sbuf[q] = Uw[SFRG[q] * 64];

    __syncthreads();

    for (int t = 0; t < T_STEPS; ++t) {
        // ---- MFMA phase ----
        I4S8 afr[8];
        #pragma unroll
        for (int kk = 0; kk < 8; ++kk)
            afr[kk].u = *(const uint4*)(smem + g_w * HM_G_STRIDE + kk * 1040 + lane * 16);

        #pragma unroll
        for (int p = 0; p < 4; ++p) {
            floatx4 acc[2];
            #pragma unroll
            for (int e = 0; e < 2; ++e)
                #pragma unroll
                for (int r = 0; r < 4; ++r) acc[e][r] = 0.f;

            // LDS frag (kk==4) for each nt of this pair (nt<7)
            uint4 lb[2];
            #pragma unroll
            for (int e = 0; e < 2; ++e) {
                const int nt = 2 * p + e;
                if (nt < 7)
                    lb[e] = *(const uint4*)(smem + ULDS_OFF + w * ULDS_W + nt * 1024 + lane * 16);
            }

            #pragma unroll
            for (int kk = 0; kk < 8; ++kk) {
                #pragma unroll
                for (int e = 0; e < 2; ++e) {
                    const int nt = 2 * p + e;
                    I4S8 bb;
                    if (kk < 4) {
                        bb.u = ures[nt * 4 + kk];
                    } else if (kk == 4 && nt < 7) {
                        bb.u = lb[e];
                    } else {
                        const int o = SORD[nt][kk];
                        bb.u = sbuf[o % SDEPTH];
                        // ring refill; wraps into next step's ordinals.
                        // slot stays o%5 because 25 % SDEPTH == 0.
                        const int nx = (o + SDEPTH < 25) ? (o + SDEPTH) : (o + SDEPTH - 25);
                        sbuf[o % SDEPTH] = Uw[SFRG[nx] * 64];
                    }
                    acc[e] = __builtin_amdgcn_mfma_f32_16x16x32_bf16(afr[kk].s, bb.s, acc[e], 0, 0, 0);
                }
            }
            // write st (fp32); bit-4 XOR on column by writer batch-quadrant parity
            // spreads the 4 lane-quadrants over all 32 banks (2-way = free)
            #pragma unroll
            for (int e = 0; e < 2; ++e) {
                const int nt = 2 * p + e;
                int kcol  = khalf * 128 + nt * 16 + (lane & 15);
                int kswz  = kcol ^ (((lane >> 4) & 1) << 4);
                int brow4 = (lane >> 4) * 4;
                #pragma unroll
                for (int r = 0; r < 4; ++r)
                    st[((brow4 + r) * 4 + g_w) * ST_ROW + kswz] = acc[e][r];
            }
        }
        __syncthreads();

        // ---- epilogue ----
        float sg[4][8];
        #pragma unroll
        for (int g = 0; g < 4; ++g) {
            const float* strow = st + ((be * 4 + g) * ST_ROW + (k8 ^ sw_e));
            float4 lo = *(const float4*)(strow);
            float4 hi = *(const float4*)(strow + 4);
            sg[g][0] = lo.x; sg[g][1] = lo.y; sg[g][2] = lo.z; sg[g][3] = lo.w;
            sg[g][4] = hi.x; sg[g][5] = hi.y; sg[g][6] = hi.z; sg[g][7] = hi.w;
            const ushort* xs = (const ushort*)&xpn[g];
            #pragma unroll
            for (int j = 0; j < 8; ++j) sg[g][j] += bf2f(xs[j]);
        }
        // refill xpre prefetch for t+1 (issued early; completes under the
        // rest of the epilogue before the barrier drain)
        {
            const int tn = (t + 1 < T_STEPS) ? t + 1 : t;
            #pragma unroll
            for (int g = 0; g < 4; ++g)
                xpn[g] = *(const uint4*)(xpre + (((size_t)tn * B_SZ + (b0 + be)) * 4 + g) * H_SZ + k8);
        }
        #pragma unroll
        for (int j = 0; j < 8; ++j) {
            float iv = fast_sigmoid(sg[0][j]);
            float fv = fast_sigmoid(sg[1][j]);
            float ov = fast_sigmoid(sg[2][j]);
            float gv = fast_tanh(sg[3][j]);
            float c  = fv * c8[j] + iv * gv;
            c8[j] = c;
            h8[j] = ov * fast_tanh(c);
        }
        {
            float* op = out + ((size_t)t * B_SZ + (b0 + be)) * H_SZ + k8;
            *(float4*)(op)     = make_float4(h8[0], h8[1], h8[2], h8[3]);
            *(float4*)(op + 4) = make_float4(h8[4], h8[5], h8[6], h8[7]);
        }
        // hm = h * zh -> LDS A-frag layout
        #pragma unroll
        for (int g = 0; g < 4; ++g) {
            const ushort* zs = (const ushort*)&zhreg[g];
            uint4 pk;
            pk.x = (uint)f2bf(h8[0] * bf2f(zs[0])) | ((uint)f2bf(h8[1] * bf2f(zs[1])) << 16);
            pk.y = (uint)f2bf(h8[2] * bf2f(zs[2])) | ((uint)f2bf(h8[3] * bf2f(zs[3])) << 16);
            pk.z = (uint)f2bf(h8[4] * bf2f(zs[4])) | ((uint)f2bf(h8[5] * bf2f(zs[5])) << 16);
            pk.w = (uint)f2bf(h8[6] * bf2f(zs[6])) | ((uint)f2bf(h8[7] * bf2f(zs[7])) << 16);
            *(uint4*)(smem + g * HM_G_STRIDE + kk_e * 1040 + lane_hm * 16) = pk;
        }
        if (t == T_STEPS - 1) {
            size_t tail = (size_t)T_STEPS * B_SZ * H_SZ;
            float* hp = out + tail + (size_t)(b0 + be) * H_SZ + k8;
            float* cp = hp + (size_t)B_SZ * H_SZ;
            *(float4*)(hp)     = make_float4(h8[0], h8[1], h8[2], h8[3]);
            *(float4*)(hp + 4) = make_float4(h8[4], h8[5], h8[6], h8[7]);
            *(float4*)(cp)     = make_float4(c8[0], c8[1], c8[2], c8[3]);
            *(float4*)(cp + 4) = make_float4(c8[4], c8[5], c8[6], c8[7]);
        }
        __syncthreads();
    }
}

// ---------- launch ----------
extern "C" void kernel_launch(void* const* d_in, const int* in_sizes, int n_in,
                              void* d_out, int out_size, void* d_ws, size_t ws_size,
                              hipStream_t stream) {
    const float* input = (const float*)d_in[0];
    const float* ux    = (const float*)d_in[1];
    const float* uh    = (const float*)d_in[2];
    const float* W     = (const float*)d_in[3];
    const float* Wb    = (const float*)d_in[4];
    const float* U     = (const float*)d_in[5];
    const float* Ub    = (const float*)d_in[6];
    float* out = (float*)d_out;

    // workspace layout (16B aligned)
    float* zx            = (float*)d_ws;                                   // 131072 f32
    __hip_bfloat16* zh   = (__hip_bfloat16*)(zx + 4 * B_SZ * I_SZ);        // 131072 bf16
    __hip_bfloat16* U_sw = zh + 4 * B_SZ * H_SZ;                           // 262144 bf16
    __hip_bfloat16* W_sw = U_sw + 4 * H_SZ * H_SZ;                         // 262144 bf16
    __hip_bfloat16* xpre = W_sw + 4 * H_SZ * I_SZ;                         // T*B*4*H bf16

    mask_kernel<<<dim3(1024), dim3(256), 0, stream>>>(ux, uh, zx, zh);
    uswz_kernel<<<dim3(128), dim3(256), 0, stream>>>(U, U_sw);
    uswz_kernel<<<dim3(128), dim3(256), 0, stream>>>(W, W_sw);

    xpre_mfma_kernel<<<dim3(1024), dim3(512), 0, stream>>>(input, zx, W_sw, Wb, Ub, xpre);

    scan_mfma_kernel<<<dim3(SCAN_BLOCKS), dim3(SCAN_THREADS), SMEM_BYTES, stream>>>(
        xpre, zh, U_sw, out);
}

// Round 5
// 4499.422 us; speedup vs baseline: 1.1079x; 1.1079x over previous
//
#include <hip/hip_runtime.h>
#include <hip/hip_bf16.h>

#define T_STEPS 512
#define B_SZ    128
#define I_SZ    256
#define H_SZ    256
#define NB      16                 // batches per scan block
#define SCAN_BLOCKS (B_SZ / NB)    // 8
#define SCAN_THREADS 512

typedef __attribute__((ext_vector_type(8))) short short8;
typedef __attribute__((ext_vector_type(4))) float floatx4;
union I4S8 { uint4 u; short8 s; };

// ---- scan LDS layout (one barrier/step, in-register gate combine) ----
// hm double-buffered: phase reads buf (t&1); epilogue writes buf (t&1)^1.
#define HMB_STRIDE 33280                 // one hm buffer: g*8320 + kk*1040 + lane*16
#define ULDS_OFF   (2 * HMB_STRIDE)      // 66560
#define ULDS_W     7168                  // 7 frags * 1024 per wave
#define SMEM_BYTES (ULDS_OFF + 8 * ULDS_W)   // 123904  (< 160 KiB; 1 block/CU)

// ---- U-frag tiering per wave (64 frags = g(4) x e(2) x kk(8)) ----
// wave n owns ktiles {2n, 2n+1} (cols n*32 .. n*32+31) for ALL FOUR gates.
// kk 0..3, g in {0,1,2}      : register-resident (24 frags = 96 VGPR; 32 would
//                              blow the 256/thread cap of a 512-thread block)
// kk == 4, slot g*2+e < 7    : LDS (7 frags)
// rest (33)                  : streamed, 4-deep rotating pipeline (o&3),
//                              restarts each step (no cross-step ring)
// consumption order: g asc, kk asc, e asc.
// OFS[o] = uint4 offset from UB: g*8192 + e*512 + kk*64
static constexpr int SORD2[4][8][2] = {
    { {-1,-1},{-1,-1},{-1,-1},{-1,-1},{-1,-1},{ 0, 1},{ 2, 3},{ 4, 5} },   // g0
    { {-1,-1},{-1,-1},{-1,-1},{-1,-1},{-1,-1},{ 6, 7},{ 8, 9},{10,11} },   // g1
    { {-1,-1},{-1,-1},{-1,-1},{-1,-1},{-1,-1},{12,13},{14,15},{16,17} },   // g2
    { {18,19},{20,21},{22,23},{24,25},{-1,26},{27,28},{29,30},{31,32} },   // g3
};
static constexpr int OFS[33] = {
      320,   832,   384,   896,   448,   960,              // g0 kk5..7 (e0,e1)
     8512,  9024,  8576,  9088,  8640,  9152,              // g1 kk5..7
    16704, 17216, 16768, 17280, 16832, 17344,              // g2 kk5..7
    24576, 25088, 24640, 25152, 24704, 25216, 24768, 25280,// g3 kk0..3 (e0,e1)
    25344,                                                 // g3 kk4 e1
    24896, 25408, 24960, 25472, 25024, 25536               // g3 kk5..7
};

__device__ __forceinline__ float fast_sigmoid(float x) {
    return 1.f / (1.f + __expf(-x));
}
__device__ __forceinline__ float fast_tanh(float x) {
    float ax = fabsf(x);
    float e = __expf(-2.f * ax);
    float t = (1.f - e) / (1.f + e);
    return copysignf(t, x);
}
__device__ __forceinline__ ushort f2bf(float v) {
    __hip_bfloat16 hb = __float2bfloat16(v);
    return *(ushort*)&hb;
}
__device__ __forceinline__ float bf2f(ushort u) {
    unsigned int b = ((unsigned int)u) << 16;
    return __uint_as_float(b);
}
__device__ __forceinline__ float concrete_mask(float u) {
    const float EPS = 1e-7f;
    float logit_p = logf(0.25f + EPS) - logf(0.75f + EPS);
    float lu = logf(u + EPS) - logf(1.0f - u + EPS);
    float z = (logit_p + lu) * 10.0f;
    float sig = 1.0f / (1.0f + expf(-z));
    return (1.0f - sig) * (1.0f / 0.75f);
}

// ---------- kernel 1: masks (zx fp32, zh bf16) ----------
__global__ void mask_kernel(const float* __restrict__ ux, const float* __restrict__ uh,
                            float* __restrict__ zx, __hip_bfloat16* __restrict__ zh) {
    int idx = blockIdx.x * blockDim.x + threadIdx.x;   // 0 .. 262143
    const int n = 4 * B_SZ * I_SZ;
    if (idx < n) zx[idx] = concrete_mask(ux[idx]);
    else         zh[idx - n] = __float2bfloat16(concrete_mask(uh[idx - n]));
}

// ---------- kernel 2: swizzle a [4][256][256] fp32 matrix into MFMA B-frag bf16 ----------
// frag (g, ktile, kk): lane l holds B[k=kk*32+((l>>4)&3)*8+j][n=ktile*16+(l&15)],
// B[k][n] = M[g][n][k].  uint4 index = ((g*16+ktile)*8+kk)*64+lane.
__global__ void uswz_kernel(const float* __restrict__ M, __hip_bfloat16* __restrict__ M_sw) {
    int tId = blockIdx.x * 256 + threadIdx.x;    // 0 .. 32767
    int lane  = tId & 63;
    int kk    = (tId >> 6) & 7;
    int ktile = (tId >> 9) & 15;
    int g     = tId >> 13;
    int nCol  = ktile * 16 + (lane & 15);
    int h0    = kk * 32 + ((lane >> 4) & 3) * 8;
    const float* src = M + ((size_t)g * 256 + nCol) * 256 + h0;
    ushort o[8];
    #pragma unroll
    for (int j = 0; j < 8; ++j) o[j] = f2bf(src[j]);
    uint4 pk;
    pk.x = (uint)o[0] | ((uint)o[1] << 16);
    pk.y = (uint)o[2] | ((uint)o[3] << 16);
    pk.z = (uint)o[4] | ((uint)o[5] << 16);
    pk.w = (uint)o[6] | ((uint)o[7] << 16);
    ((uint4*)M_sw)[tId] = pk;
}

// ---------- kernel 3: x_pre via MFMA (masked input @ W^T + Wb + Ub), bf16 out ----------
// Output layout is PRE-SWIZZLED for the scan's per-lane epilogue:
//   xpre[t][blk][tid(512)][g(4)][idx8(8)]  where tid = n*64+lane,
//   cell (b = blk*16 + (lane>>4)*4 + r, col = n*32 + e*16 + (lane&15)), idx8 = e*4+r.
__global__ __launch_bounds__(512, 2) void xpre_mfma_kernel(
        const float* __restrict__ input, const float* __restrict__ zx,
        const __hip_bfloat16* __restrict__ W_sw,
        const float* __restrict__ Wb, const float* __restrict__ Ub,
        __hip_bfloat16* __restrict__ xpre) {
    const int tid   = threadIdx.x;
    const int w     = tid >> 6;
    const int lane  = tid & 63;
    const int g     = w >> 1;
    const int khalf = w & 1;
    const int row0  = blockIdx.x * 64;
    const int mrow  = lane & 15;
    const int kq    = lane >> 4;     // 0..3

    floatx4 acc[4][8];
    #pragma unroll
    for (int mt = 0; mt < 4; ++mt)
        #pragma unroll
        for (int nt = 0; nt < 8; ++nt)
            #pragma unroll
            for (int r = 0; r < 4; ++r) acc[mt][nt][r] = 0.f;

    const uint4* Wp = (const uint4*)W_sw + ((size_t)((g * 16 + khalf * 8) * 8)) * 64 + lane;

    for (int kc = 0; kc < 8; ++kc) {
        I4S8 af[4];
        const int i0 = kc * 32 + kq * 8;
        #pragma unroll
        for (int mt = 0; mt < 4; ++mt) {
            int row = row0 + mt * 16 + mrow;
            int b   = row & (B_SZ - 1);
            const float4* ip = (const float4*)(input + (size_t)row * I_SZ + i0);
            const float4* zp = (const float4*)(zx + ((size_t)g * B_SZ + b) * I_SZ + i0);
            float4 a0 = ip[0], a1 = ip[1];
            float4 z0 = zp[0], z1 = zp[1];
            uint4 pk;
            pk.x = (uint)f2bf(a0.x * z0.x) | ((uint)f2bf(a0.y * z0.y) << 16);
            pk.y = (uint)f2bf(a0.z * z0.z) | ((uint)f2bf(a0.w * z0.w) << 16);
            pk.z = (uint)f2bf(a1.x * z1.x) | ((uint)f2bf(a1.y * z1.y) << 16);
            pk.w = (uint)f2bf(a1.z * z1.z) | ((uint)f2bf(a1.w * z1.w) << 16);
            af[mt].u = pk;
        }
        #pragma unroll
        for (int nt = 0; nt < 8; ++nt) {
            I4S8 bb; bb.u = Wp[(nt * 8 + kc) * 64];
            #pragma unroll
            for (int mt = 0; mt < 4; ++mt)
                acc[mt][nt] = __builtin_amdgcn_mfma_f32_16x16x32_bf16(af[mt].s, bb.s, acc[mt][nt], 0, 0, 0);
        }
    }
    // epilogue: + Wb + Ub, store into the scan-swizzled xpre layout.
    // C layout: row = row0+mt*16+(lane>>4)*4+r, col = khalf*128+nt*16+(lane&15).
    #pragma unroll
    for (int nt = 0; nt < 8; ++nt) {
        int col  = khalf * 128 + nt * 16 + (lane & 15);
        float bias = Wb[g * H_SZ + col] + Ub[g * H_SZ + col];
        int np = col >> 5;           // scan wave
        int e  = (col >> 4) & 1;
        #pragma unroll
        for (int mt = 0; mt < 4; ++mt) {
            int row = row0 + mt * 16 + (lane >> 4) * 4;   // r = 0
            int t   = row >> 7;
            int b   = row & (B_SZ - 1);
            int blk = b >> 4;
            int bi  = b & 15;                              // = (lane>>4)*4 (r=0)
            int tidp = np * 64 + (((bi >> 2) << 4) | (col & 15));
            ushort q0 = f2bf(acc[mt][nt][0] + bias);
            ushort q1 = f2bf(acc[mt][nt][1] + bias);
            ushort q2 = f2bf(acc[mt][nt][2] + bias);
            ushort q3 = f2bf(acc[mt][nt][3] + bias);
            uint2 pk2;
            pk2.x = (uint)q0 | ((uint)q1 << 16);
            pk2.y = (uint)q2 | ((uint)q3 << 16);
            size_t dst = ((((size_t)t * SCAN_BLOCKS + blk) * 512 + tidp) * 4 + g) * 8 + e * 4;
            *(uint2*)(xpre + dst) = pk2;   // covers idx8 = e*4 + {0,1,2,3}
        }
    }
}

// ---------- kernel 4: MFMA scan, one barrier/step, in-register gate combine ----------
// Wave n computes ALL 4 gates for cols [n*32, n*32+32) x 16 batches.
// Lane owns cells (b = b0+(lane>>4)*4+r, c = n*32+e*16+(lane&15)), r=0..3, e=0..1.
__global__ __launch_bounds__(SCAN_THREADS, 1) void scan_mfma_kernel(
        const __hip_bfloat16* __restrict__ xpre,   // swizzled [t][blk][tid][g][8]
        const __hip_bfloat16* __restrict__ zh,     // [4][B][H] bf16
        const __hip_bfloat16* __restrict__ U_sw,   // swizzled B-frags
        float* __restrict__ out) {
    extern __shared__ __align__(16) char smem[];
    const int tid  = threadIdx.x;
    const int blk  = blockIdx.x;
    const int b0   = blk * NB;
    const int n    = tid >> 6;      // wave 0..7
    const int lane = tid & 63;

    // per-wave U base: uint4 idx = g*8192 + n*1024 + e*512 + kk*64 + lane
    const uint4* UB = (const uint4*)U_sw + n * 1024 + lane;

    // ---- one-time fills ----
    uint4 ures[24];                  // kk 0..3 for g in {0,1,2}: index (g*2+e)*4+kk
    #pragma unroll
    for (int g2 = 0; g2 < 6; ++g2)
        #pragma unroll
        for (int kk = 0; kk < 4; ++kk)
            ures[g2 * 4 + kk] = UB[(g2 >> 1) * 8192 + (g2 & 1) * 512 + kk * 64];
    // LDS frags: kk==4, slot g*2+e for slots 0..6
    #pragma unroll
    for (int f = 0; f < 7; ++f) {
        uint4 v = UB[(f >> 1) * 8192 + (f & 1) * 512 + 4 * 64];
        *(uint4*)(smem + ULDS_OFF + n * ULDS_W + f * 1024 + lane * 16) = v;
    }
    // zero hm buffer 0 (h0 = 0)
    for (int i = tid; i < HMB_STRIDE / 16; i += SCAN_THREADS)
        ((uint4*)smem)[i] = make_uint4(0u, 0u, 0u, 0u);

    // zh for this lane's cells: zpk[g][i>>1] packs idx8 pairs (i = e*4+r)
    uint zpk[4][4];
    #pragma unroll
    for (int g = 0; g < 4; ++g)
        #pragma unroll
        for (int e = 0; e < 2; ++e)
            #pragma unroll
            for (int rp = 0; rp < 2; ++rp) {
                const __hip_bfloat16* zp = zh
                    + ((size_t)(g * B_SZ + b0 + (lane >> 4) * 4 + rp * 2)) * H_SZ
                    + n * 32 + e * 16 + (lane & 15);
                ushort lo = *(const ushort*)zp;
                ushort hi = *(const ushort*)(zp + H_SZ);     // next batch row
                zpk[g][e * 2 + rp] = (uint)lo | ((uint)hi << 16);
            }

    float c8[8], h8[8];
    #pragma unroll
    for (int j = 0; j < 8; ++j) c8[j] = 0.f;

    // per-lane hm write base (A-frag: lane_a = b_r | (e*2 + ((lane&15)>>3))<<4, j = lane&7)
    const int hm_lane_off = n * 1040 + (((lane & 15) >> 3) << 8)
                          + ((lane >> 4) * 4) * 16 + (lane & 7) * 2;

    __syncthreads();

    for (int t = 0; t < T_STEPS; ++t) {
        const char* hr = smem + (t & 1) * HMB_STRIDE + lane * 16;          // phase reads
        char* hw = smem + ((t & 1) ^ 1) * HMB_STRIDE + hm_lane_off;        // epilogue writes

        // phase-top global loads: xpre for this step (covered by 64 MFMAs)
        uint4 xpn[4];
        #pragma unroll
        for (int g = 0; g < 4; ++g)
            xpn[g] = *(const uint4*)(xpre +
                ((((size_t)t * SCAN_BLOCKS + blk) * 512 + tid) * 4 + g) * 8);
        // stream seeds (ordinals 0..3)
        uint4 sbuf[4];
        #pragma unroll
        for (int q = 0; q < 4; ++q) sbuf[q] = UB[OFS[q]];

        floatx4 acc[8];              // (g*2+e)
        #pragma unroll
        for (int a = 0; a < 8; ++a)
            #pragma unroll
            for (int r = 0; r < 4; ++r) acc[a][r] = 0.f;

        #pragma unroll
        for (int g = 0; g < 4; ++g) {
            I4S8 afr[8];
            #pragma unroll
            for (int kk = 0; kk < 8; ++kk)
                afr[kk].u = *(const uint4*)(hr + g * 8320 + kk * 1040);
            uint4 lb[2];
            lb[0] = *(const uint4*)(smem + ULDS_OFF + n * ULDS_W + (g * 2) * 1024 + lane * 16);
            if (g < 3)
                lb[1] = *(const uint4*)(smem + ULDS_OFF + n * ULDS_W + (g * 2 + 1) * 1024 + lane * 16);

            #pragma unroll
            for (int kk = 0; kk < 8; ++kk) {
                #pragma unroll
                for (int e = 0; e < 2; ++e) {
                    I4S8 bb;
                    if (g < 3 && kk < 4) {
                        bb.u = ures[(g * 2 + e) * 4 + kk];
                    } else if (kk == 4 && !(g == 3 && e == 1)) {
                        bb.u = lb[e];
                    } else {
                        const int o = SORD2[g][kk][e];
                        bb.u = sbuf[o & 3];
                        if (o + 4 < 33) sbuf[o & 3] = UB[OFS[o + 4]];
                    }
                    acc[g * 2 + e] = __builtin_amdgcn_mfma_f32_16x16x32_bf16(
                        afr[kk].s, bb.s, acc[g * 2 + e], 0, 0, 0);
                }
            }
        }

        // ---- in-register epilogue (no barrier needed: all own-wave data) ----
        float sg[4][8];
        #pragma unroll
        for (int g = 0; g < 4; ++g) {
            const ushort* xs = (const ushort*)&xpn[g];
            #pragma unroll
            for (int i = 0; i < 8; ++i)
                sg[g][i] = acc[g * 2 + (i >> 2)][i & 3] + bf2f(xs[i]);
        }
        #pragma unroll
        for (int i = 0; i < 8; ++i) {
            float iv = fast_sigmoid(sg[0][i]);
            float fv = fast_sigmoid(sg[1][i]);
            float ov = fast_sigmoid(sg[2][i]);
            float gv = fast_tanh(sg[3][i]);
            float c  = fv * c8[i] + iv * gv;
            c8[i] = c;
            h8[i] = ov * fast_tanh(c);
        }
        {
            float* ob = out + ((size_t)t * B_SZ + b0 + (lane >> 4) * 4) * H_SZ
                      + n * 32 + (lane & 15);
            #pragma unroll
            for (int e = 0; e < 2; ++e)
                #pragma unroll
                for (int r = 0; r < 4; ++r)
                    ob[(size_t)r * H_SZ + e * 16] = h8[e * 4 + r];
        }
        // hm = h * zh -> A-frag layout, buffer t^1 (kk region = n)
        #pragma unroll
        for (int g = 0; g < 4; ++g)
            #pragma unroll
            for (int e = 0; e < 2; ++e)
                #pragma unroll
                for (int r = 0; r < 4; ++r) {
                    const int i = e * 4 + r;
                    ushort zv = (ushort)(zpk[g][i >> 1] >> ((i & 1) * 16));
                    ushort hv = f2bf(h8[i] * bf2f(zv));
                    *(ushort*)(hw + g * 8320 + e * 512 + r * 16) = hv;
                }

        if (t == T_STEPS - 1) {
            size_t tail = (size_t)T_STEPS * B_SZ * H_SZ;
            float* hp = out + tail + (size_t)(b0 + (lane >> 4) * 4) * H_SZ
                      + n * 32 + (lane & 15);
            float* cp = hp + (size_t)B_SZ * H_SZ;
            #pragma unroll
            for (int e = 0; e < 2; ++e)
                #pragma unroll
                for (int r = 0; r < 4; ++r) {
                    hp[(size_t)r * H_SZ + e * 16] = h8[e * 4 + r];
                    cp[(size_t)r * H_SZ + e * 16] = c8[e * 4 + r];
                }
        }
        __syncthreads();   // hm[t^1] complete before next phase reads it
    }
}

// ---------- launch ----------
extern "C" void kernel_launch(void* const* d_in, const int* in_sizes, int n_in,
                              void* d_out, int out_size, void* d_ws, size_t ws_size,
                              hipStream_t stream) {
    const float* input = (const float*)d_in[0];
    const float* ux    = (const float*)d_in[1];
    const float* uh    = (const float*)d_in[2];
    const float* W     = (const float*)d_in[3];
    const float* Wb    = (const float*)d_in[4];
    const float* U     = (const float*)d_in[5];
    const float* Ub    = (const float*)d_in[6];
    float* out = (float*)d_out;

    // workspace layout (16B aligned)
    float* zx            = (float*)d_ws;                                   // 131072 f32
    __hip_bfloat16* zh   = (__hip_bfloat16*)(zx + 4 * B_SZ * I_SZ);        // 131072 bf16
    __hip_bfloat16* U_sw = zh + 4 * B_SZ * H_SZ;                           // 262144 bf16
    __hip_bfloat16* W_sw = U_sw + 4 * H_SZ * H_SZ;                         // 262144 bf16
    __hip_bfloat16* xpre = W_sw + 4 * H_SZ * I_SZ;                         // T*B*4*H bf16

    mask_kernel<<<dim3(1024), dim3(256), 0, stream>>>(ux, uh, zx, zh);
    uswz_kernel<<<dim3(128), dim3(256), 0, stream>>>(U, U_sw);
    uswz_kernel<<<dim3(128), dim3(256), 0, stream>>>(W, W_sw);

    xpre_mfma_kernel<<<dim3(1024), dim3(512), 0, stream>>>(input, zx, W_sw, Wb, Ub, xpre);

    scan_mfma_kernel<<<dim3(SCAN_BLOCKS), dim3(SCAN_THREADS), SMEM_BYTES, stream>>>(
        xpre, zh, U_sw, out);
}